// Round 4
// baseline (273.816 us; speedup 1.0000x reference)
//
#include <hip/hip_runtime.h>
#include <hip/hip_bf16.h>

#define G_      4
#define NVP     3000
#define NCP     1000
#define DEG     8
#define NV      (G_*NVP)      // 12000
#define NC      (G_*NCP)      // 4000
#define NN      (NV+NC)       // 16000
#define NE      (NV*DEG)      // 96000
#define EPG     (NVP*DEG)     // 24000 edges per graph
#define DF      64
#define DH      128
#define DO      64
#define KB      8
#define NB      (G_*KB)       // 32 break nodes
#define MAXR    96
#define MAXJ    640

// ---------------- fused setup: count/scan/fill/sort/nodeval/topk, one block per graph ----------------
__global__ __launch_bounds__(1024) void k_setup(
    const int* __restrict__ conArr,
    int* __restrict__ csr_off, int* __restrict__ csr_e, int* __restrict__ csr_v,
    float* __restrict__ dinv, float* __restrict__ nodeval, int* __restrict__ breakix)
{
    __shared__ int   cnt[NCP];
    __shared__ int   cur[NCP];
    __shared__ int   loff[NCP];
    __shared__ float dinvC[NCP];
    __shared__ float nvl[NVP + NCP];
    __shared__ int   wtmp[16];
    __shared__ float mv[16]; __shared__ int mp[16];

    int g = blockIdx.x;
    int tid = threadIdx.x, lane = tid & 63, w = tid >> 6;
    int ebase = g * EPG;

    // A: zero counts
    if (tid < NCP) cnt[tid] = 0;
    __syncthreads();
    // B: count (LDS atomics)
    for (int e = tid; e < EPG; e += 1024)
        atomicAdd(&cnt[conArr[ebase + e] - g*NCP], 1);
    __syncthreads();
    // C: block scan + dinv
    int x = (tid < NCP) ? cnt[tid] : 0;
    int orig = x;
    for (int o = 1; o < 64; o <<= 1) { int y = __shfl_up(x, o); if (lane >= o) x += y; }
    if (lane == 63) wtmp[w] = x;
    __syncthreads();
    if (tid == 0) { int run = 0; for (int t = 0; t < 16; ++t) { int v = wtmp[t]; wtmp[t] = run; run += v; } }
    __syncthreads();
    int excl = x + wtmp[w] - orig;
    if (tid < NCP) {
        loff[tid] = excl; cur[tid] = excl;
        float dc = 1.0f / sqrtf((float)(orig + 1));
        dinvC[tid] = dc;
        dinv[NV + g*NCP + tid] = dc;
        csr_off[g*NCP + tid] = ebase + excl;
    }
    if (g == 0 && tid == 0) csr_off[NC] = NE;
    for (int i = tid; i < NVP; i += 1024) dinv[g*NVP + i] = (1.0f/3.0f);
    __syncthreads();
    // D: fill (store global edge ids; order nondeterministic, fixed by sort below)
    for (int e = tid; e < EPG; e += 1024) {
        int c = conArr[ebase + e] - g*NCP;
        int p = atomicAdd(&cur[c], 1);
        csr_e[ebase + p] = ebase + e;
    }
    __syncthreads();
    // E: per-row rank sort by edge id (unique keys), emit csr_v (var = eid>>3)
    for (int row = w; row < NCP; row += 16) {
        int s = loff[row], len = cnt[row];
        if (len <= 64) {
            int key = (lane < len) ? csr_e[ebase + s + lane] : 0x7fffffff;
            int rank = 0;
            for (int m = 0; m < len; ++m) {
                int km = __shfl(key, m);
                if (lane < len && km < key) rank++;
            }
            if (lane < len) csr_v[ebase + s + rank] = key >> 3;
        } else if (lane == 0) {
            for (int a = 1; a < len; ++a) {
                int k2 = csr_e[ebase+s+a]; int b2 = a-1;
                while (b2 >= 0 && csr_e[ebase+s+b2] > k2) { csr_e[ebase+s+b2+1] = csr_e[ebase+s+b2]; --b2; }
                csr_e[ebase+s+b2+1] = k2;
            }
            for (int p = 0; p < len; ++p) csr_v[ebase+s+p] = csr_e[ebase+s+p] >> 3;
        }
    }
    // F: nodeval (rowsum of A_hat) -- graph-local
    const float dv3 = (1.0f/3.0f);
    for (int v = tid; v < NVP; v += 1024) {
        float s = 0.f;
        int e0 = (g*NVP + v)*DEG;
        #pragma unroll
        for (int k = 0; k < DEG; ++k) s += dv3 * dinvC[conArr[e0+k] - g*NCP];
        float val = s + dv3*dv3;
        nvl[v] = val;
        nodeval[g*NVP + v] = val;
    }
    for (int c = tid; c < NCP; c += 1024) {
        float dc = dinvC[c];
        float val = (float)cnt[c] * (dc * dv3) + dc*dc;   // equal-degree cons get identical bits
        nvl[NVP + c] = val;
        nodeval[NV + g*NCP + c] = val;
    }
    __syncthreads();
    // H: top-8, tie -> lower local position (matches lax.top_k)
    for (int it = 0; it < KB; ++it) {
        float bv = -1e30f; int bp = 1 << 30;
        for (int p = tid; p < NVP+NCP; p += 1024) {
            float vv = nvl[p];
            if (vv > bv || (vv == bv && p < bp)) { bv = vv; bp = p; }
        }
        for (int o = 32; o > 0; o >>= 1) {
            float ov = __shfl_xor(bv, o); int op = __shfl_xor(bp, o);
            if (ov > bv || (ov == bv && op < bp)) { bv = ov; bp = op; }
        }
        if (lane == 0) { mv[w] = bv; mp[w] = bp; }
        __syncthreads();
        if (tid == 0) {
            float fv = mv[0]; int fp = mp[0];
            for (int t = 1; t < 16; ++t)
                if (mv[t] > fv || (mv[t] == fv && mp[t] < fp)) { fv = mv[t]; fp = mp[t]; }
            nvl[fp] = -1e30f;
            breakix[g*KB + it] = (fp < NVP) ? (g*NVP + fp) : (NV + g*NCP + (fp - NVP));
        }
        __syncthreads();
    }
}

// ---------------- forward ----------------

// AX = A_hat @ X  (N x 64), one row per wave
__global__ void k_spmmX(const float* __restrict__ vf, const float* __restrict__ cf,
                        const float* __restrict__ dinv, const int* __restrict__ conArr,
                        const int* __restrict__ csr_off, const int* __restrict__ csr_v,
                        float* __restrict__ AX)
{
    int i = blockIdx.x*4 + (threadIdx.x >> 6);
    int lane = threadIdx.x & 63;
    float di = dinv[i];
    float acc;
    if (i < NV) {
        acc = di * vf[(size_t)i*DF + lane];
        int e0 = i*DEG;
        #pragma unroll
        for (int k = 0; k < DEG; ++k) {
            int c = conArr[e0+k];
            acc += dinv[NV + c] * cf[(size_t)c*DF + lane];
        }
    } else {
        int c = i - NV;
        acc = di * cf[(size_t)c*DF + lane];
        int p0 = csr_off[c], p1 = csr_off[c+1];
        for (int p = p0; p < p1; ++p)
            acc += (1.0f/3.0f) * vf[(size_t)csr_v[p]*DF + lane];
    }
    AX[(size_t)i*DF + lane] = di * acc;
}

// S1 = AX @ W1 + nodeval (x) b1    (NN x 128)
__global__ __launch_bounds__(256) void k_gemm1(const float* __restrict__ AX, const float* __restrict__ W1,
                        const float* __restrict__ b1, const float* __restrict__ nodeval,
                        float* __restrict__ S1)
{
    __shared__ float W1T[128*68];   // [c][k], padded
    __shared__ float AXs[32*68];
    int tid = threadIdx.x;
    for (int t = tid; t < 64*128; t += 256) {
        int k = t >> 7, c = t & 127;
        W1T[c*68 + k] = W1[t];
    }
    int r0 = blockIdx.x * 32;
    for (int t = tid; t < 32*16; t += 256) {
        int row = t >> 4, q = t & 15;
        *(float4*)&AXs[row*68 + q*4] = *(const float4*)&AX[(size_t)(r0+row)*DF + q*4];
    }
    __syncthreads();
    int tc = tid & 15, tr = tid >> 4;
    float acc[2][8];
    #pragma unroll
    for (int r = 0; r < 2; ++r)
        #pragma unroll
        for (int j = 0; j < 8; ++j) acc[r][j] = 0.f;
    #pragma unroll
    for (int k0 = 0; k0 < 64; k0 += 4) {
        float4 a0 = *(const float4*)&AXs[(tr*2+0)*68 + k0];
        float4 a1 = *(const float4*)&AXs[(tr*2+1)*68 + k0];
        #pragma unroll
        for (int j = 0; j < 8; ++j) {
            float4 wv = *(const float4*)&W1T[(tc + 16*j)*68 + k0];  // consecutive lanes -> consecutive c
            acc[0][j] += a0.x*wv.x + a0.y*wv.y + a0.z*wv.z + a0.w*wv.w;
            acc[1][j] += a1.x*wv.x + a1.y*wv.y + a1.z*wv.z + a1.w*wv.w;
        }
    }
    #pragma unroll
    for (int r = 0; r < 2; ++r) {
        int row = r0 + tr*2 + r;
        float nv_ = nodeval[row];
        #pragma unroll
        for (int j = 0; j < 8; ++j) {
            int col = tc + 16*j;
            S1[(size_t)row*DH + col] = acc[r][j] + nv_*b1[col];
        }
    }
}

// AH = A_hat @ relu(S1) at variable rows only (NV x 128)
__global__ void k_spmmH(const float* __restrict__ S1, const float* __restrict__ dinv,
                        const int* __restrict__ conArr, float* __restrict__ AH)
{
    int v = blockIdx.x*2 + (threadIdx.x >> 7);
    int ch = threadIdx.x & 127;
    const float dv = (1.0f/3.0f);
    float acc = dv * fmaxf(S1[(size_t)v*DH + ch], 0.f);
    int e0 = v*DEG;
    #pragma unroll
    for (int k = 0; k < DEG; ++k) {
        int c = NV + conArr[e0+k];
        acc += dinv[c] * fmaxf(S1[(size_t)c*DH + ch], 0.f);
    }
    AH[(size_t)v*DH + ch] = dv * acc;
}

// out rows: AH @ W2 + nodeval (x) b2, fused LayerNorm; writes outvar, holo, d_out
__global__ __launch_bounds__(256) void k_gemm2ln(const float* __restrict__ AH, const float* __restrict__ W2,
      const float* __restrict__ b2, const float* __restrict__ nodeval,
      const float* __restrict__ gamma, const float* __restrict__ beta,
      float* __restrict__ outvar, float* __restrict__ holo, float* __restrict__ out)
{
    __shared__ float W2T[64*132];   // [c][k], padded
    __shared__ float AHs[32*132];
    __shared__ float s2[32*68];
    int tid = threadIdx.x;
    for (int t = tid; t < 128*64; t += 256) {
        int k = t >> 6, c = t & 63;
        W2T[c*132 + k] = W2[t];
    }
    int r0 = blockIdx.x * 32;
    for (int t = tid; t < 32*32; t += 256) {
        int row = t >> 5, q = t & 31;
        *(float4*)&AHs[row*132 + q*4] = *(const float4*)&AH[(size_t)(r0+row)*DH + q*4];
    }
    __syncthreads();
    int tc = tid & 15, tr = tid >> 4;
    float acc[2][4];
    #pragma unroll
    for (int r = 0; r < 2; ++r)
        #pragma unroll
        for (int j = 0; j < 4; ++j) acc[r][j] = 0.f;
    #pragma unroll
    for (int k0 = 0; k0 < 128; k0 += 4) {
        float4 a0 = *(const float4*)&AHs[(tr*2+0)*132 + k0];
        float4 a1 = *(const float4*)&AHs[(tr*2+1)*132 + k0];
        #pragma unroll
        for (int j = 0; j < 4; ++j) {
            float4 wv = *(const float4*)&W2T[(tc + 16*j)*132 + k0];
            acc[0][j] += a0.x*wv.x + a0.y*wv.y + a0.z*wv.z + a0.w*wv.w;
            acc[1][j] += a1.x*wv.x + a1.y*wv.y + a1.z*wv.z + a1.w*wv.w;
        }
    }
    #pragma unroll
    for (int r = 0; r < 2; ++r) {
        int row = tr*2 + r;
        float nv_ = nodeval[r0 + row];
        #pragma unroll
        for (int j = 0; j < 4; ++j) {
            int col = tc + 16*j;
            s2[row*68 + col] = acc[r][j] + nv_*b2[col];
        }
    }
    __syncthreads();
    int lane = tid & 63, w = tid >> 6;
    float gm = gamma[lane], bt = beta[lane];
    for (int rr = 0; rr < 8; ++rr) {
        int row = w*8 + rr;
        int v = r0 + row;
        float xv = s2[row*68 + lane];
        float s = xv;
        for (int o = 32; o > 0; o >>= 1) s += __shfl_xor(s, o);
        float mu = s * (1.f/64.f);
        float d = xv - mu;
        float vs = d*d;
        for (int o = 32; o > 0; o >>= 1) vs += __shfl_xor(vs, o);
        float rstd = 1.0f / sqrtf(vs*(1.f/64.f) + 1e-5f);
        float h = d*rstd*gm + bt;
        outvar[(size_t)v*DO + lane] = xv;
        holo  [(size_t)v*DO + lane] = h;
        out   [(size_t)v*DO + lane] = h;
    }
}

// ---------------- corrections ----------------

__global__ __launch_bounds__(256) void k_corr_a(const int* __restrict__ breakidx, const float* __restrict__ dinv,
    const int* __restrict__ conArr, const int* __restrict__ csr_off, const int* __restrict__ csr_v,
    const float* __restrict__ S1, const float* __restrict__ W1, const float* __restrict__ W2,
    int* __restrict__ RnG, float* __restrict__ RwG, int* __restrict__ nRG, float* __restrict__ dz2G)
{
    __shared__ float W2s[128*64];
    __shared__ int Rn[MAXR];
    __shared__ float Rw[MAXR];
    __shared__ float dh[4][128];
    __shared__ int nR_s;
    int b = blockIdx.x, tid = threadIdx.x, lane = tid & 63;
    int i = breakidx[b];
    for (int t = tid; t < 128*64; t += 256) W2s[t] = W2[t];
    if (tid < 64) {
        float di = dinv[i];
        if (i >= NV) {
            int c = i - NV;
            int p0 = csr_off[c], len = csr_off[c+1] - p0;
            if (len <= 64) {
                int v  = (lane < len) ? csr_v[p0 + lane] : -1;
                int pv = (lane > 0 && lane < len) ? csr_v[p0 + lane - 1] : -2;
                bool head = (lane < len) && (lane == 0 || pv != v);
                unsigned long long hm = __ballot(head);
                int nH = __popcll(hm);
                if (head) {
                    int rank = __popcll(hm & ((1ull << lane) - 1));
                    unsigned long long rest = (lane < 63) ? (hm >> (lane+1)) : 0ull;
                    int next = rest ? (lane + __ffsll((long long)rest)) : len;
                    int m = next - lane;
                    Rn[rank] = v; Rw[rank] = (float)m * dinv[v] * di;
                }
                if (lane == 0) { Rn[nH] = i; Rw[nH] = di*di; nR_s = nH + 1; }
            } else if (lane == 0) {
                int n = 0; int p = p0, e1 = p0 + len;
                while (p < e1 && n < MAXR-1) {
                    int v = csr_v[p]; int m = 1; ++p;
                    while (p < e1 && csr_v[p] == v) { ++m; ++p; }
                    Rn[n] = v; Rw[n] = (float)m * dinv[v] * di; ++n;
                }
                Rn[n] = i; Rw[n] = di*di; nR_s = n + 1;
            }
        } else if (lane == 0) {
            // variable break node (defensive; analytically never top-k)
            int cn[DEG];
            for (int k = 0; k < DEG; ++k) cn[k] = NV + conArr[i*DEG + k];
            for (int a = 1; a < DEG; ++a) { int key = cn[a]; int bb = a-1;
                while (bb >= 0 && cn[bb] > key) { cn[bb+1] = cn[bb]; --bb; } cn[bb+1] = key; }
            int n = 0, k = 0;
            while (k < DEG) { int u = cn[k]; int m = 1; ++k;
                while (k < DEG && cn[k] == u) { ++m; ++k; }
                Rn[n] = u; Rw[n] = (float)m * dinv[u] * di; ++n; }
            Rn[n] = i; Rw[n] = di*di; nR_s = n + 1;
        }
    }
    __syncthreads();
    int nR = nR_s;
    for (int t = tid; t < nR; t += 256) { RnG[b*MAXR + t] = Rn[t]; RwG[b*MAXR + t] = Rw[t]; }
    if (tid == 0) nRG[b] = nR;
    for (int r0 = 0; r0 < nR; r0 += 4) {
        __syncthreads();
        for (int t = tid; t < 512; t += 256) {
            int ty = t >> 7, k = t & 127;
            int r = r0 + ty;
            if (r < nR) {
                float s1 = S1[(size_t)Rn[r]*DH + k];
                float a = s1 + Rw[r] * W1[64*128 + k];
                dh[ty][k] = fmaxf(a, 0.f) - fmaxf(s1, 0.f);
            }
        }
        __syncthreads();
        int ty2 = tid >> 6, c = tid & 63;
        int r2 = r0 + ty2;
        if (r2 < nR) {
            float acc = 0.f;
            #pragma unroll
            for (int kk = 0; kk < 128; ++kk) acc += dh[ty2][kk] * W2s[kk*64 + c];
            dz2G[((size_t)b*MAXR + r2)*DO + c] = acc;
        }
    }
}

// per graph serial over its 8 breaks: out[j] += 0.125*(LN(out+delta)-holo[j])
__global__ void k_corr_b(const int* __restrict__ RnG, const float* __restrict__ RwG,
                         const int* __restrict__ nRG, const float* __restrict__ dz2G,
                         const int* __restrict__ breakidx, const float* __restrict__ dinv,
                         const int* __restrict__ conArr, const int* __restrict__ csr_off,
                         const int* __restrict__ csr_v,
                         const float* __restrict__ outvar, const float* __restrict__ holo,
                         const float* __restrict__ gamma, const float* __restrict__ beta,
                         float* __restrict__ out) {
    int g = blockIdx.x;
    int lane = threadIdx.x & 63, wv = threadIdx.x >> 6; // 16 waves
    __shared__ int Jn[MAXJ];
    __shared__ int nJ_s;
    for (int bi = 0; bi < KB; ++bi) {
        int b = g*KB + bi;
        int i = breakidx[b];
        int nR = nRG[b];
        if (i >= NV) {
            int nJ = nR - 1;
            const float* dzi = &dz2G[((size_t)b*MAXR + (nR-1))*DO];
            for (int j0 = wv; j0 < nJ; j0 += 16) {
                int j = RnG[b*MAXR + j0];
                float aji = RwG[b*MAXR + j0];
                float dj = dinv[j];
                float x = outvar[(size_t)j*DO + lane]
                        + aji * dzi[lane]
                        + dj*dj * dz2G[((size_t)b*MAXR + j0)*DO + lane];
                float s = x; for (int o = 32; o > 0; o >>= 1) s += __shfl_xor(s, o);
                float mu = s * (1.f/64.f);
                float d = x - mu;
                float vs = d*d; for (int o = 32; o > 0; o >>= 1) vs += __shfl_xor(vs, o);
                float rstd = 1.0f / sqrtf(vs*(1.f/64.f) + 1e-5f);
                float hn = d*rstd*gamma[lane] + beta[lane];
                out[(size_t)j*DO + lane] += 0.125f * (hn - holo[(size_t)j*DO + lane]);
            }
        } else {
            if (threadIdx.x == 0) {
                int n = 0; Jn[n++] = i;
                for (int r = 0; r < nR-1; ++r) {
                    int c = RnG[b*MAXR + r] - NV;
                    for (int p = csr_off[c]; p < csr_off[c+1]; ++p) {
                        int u = csr_v[p];
                        if (p > csr_off[c] && csr_v[p-1] == u) continue;
                        bool found = false;
                        for (int q = 0; q < n; ++q) if (Jn[q] == u) { found = true; break; }
                        if (!found && n < MAXJ) Jn[n++] = u;
                    }
                }
                nJ_s = n;
            }
            __syncthreads();
            int nJ = nJ_s;
            for (int j0 = wv; j0 < nJ; j0 += 16) {
                int j = Jn[j0];
                float dj = dinv[j];
                float x = outvar[(size_t)j*DO + lane];
                for (int k = 0; k < DEG; ++k) {
                    int cn = NV + conArr[j*DEG + k];
                    for (int r = 0; r < nR-1; ++r)
                        if (RnG[b*MAXR + r] == cn) {
                            x += dj * dinv[cn] * dz2G[((size_t)b*MAXR + r)*DO + lane];
                            break;
                        }
                }
                if (j == i) x += dj*dj * dz2G[((size_t)b*MAXR + nR-1)*DO + lane];
                float s = x; for (int o = 32; o > 0; o >>= 1) s += __shfl_xor(s, o);
                float mu = s * (1.f/64.f);
                float d = x - mu;
                float vs = d*d; for (int o = 32; o > 0; o >>= 1) vs += __shfl_xor(vs, o);
                float rstd = 1.0f / sqrtf(vs*(1.f/64.f) + 1e-5f);
                float hn = d*rstd*gamma[lane] + beta[lane];
                out[(size_t)j*DO + lane] += 0.125f * (hn - holo[(size_t)j*DO + lane]);
            }
        }
        __syncthreads();
    }
}

// ---------------- launch ----------------

extern "C" void kernel_launch(void* const* d_in, const int* in_sizes, int n_in,
                              void* d_out, int out_size, void* d_ws, size_t ws_size,
                              hipStream_t stream) {
    const float* vf    = (const float*)d_in[0];
    const float* cf    = (const float*)d_in[1];
    const float* W1    = (const float*)d_in[2];
    const float* b1    = (const float*)d_in[3];
    const float* W2    = (const float*)d_in[4];
    const float* b2    = (const float*)d_in[5];
    const float* gamma = (const float*)d_in[6];
    const float* beta  = (const float*)d_in[7];
    const int*   ei    = (const int*)d_in[8];   // [0..NE) = con, [NE..2NE) = var
    const int*   conArr = ei;
    float* out = (float*)d_out;

    char* ws = (char*)d_ws;
    size_t off = 0;
    auto alloc = [&](size_t bytes) { char* p = ws + off; off = (off + bytes + 255) & ~(size_t)255; return p; };
    float* dinv    = (float*)alloc(NN*4);
    int*   csr_off = (int*)  alloc((NC+1)*4);
    int*   csr_e   = (int*)  alloc(NE*4);
    int*   csr_v   = (int*)  alloc(NE*4);
    float* nodeval = (float*)alloc(NN*4);
    int*   breakix = (int*)  alloc(NB*4);
    float* AX      = (float*)alloc((size_t)NN*DF*4);
    float* S1      = (float*)alloc((size_t)NN*DH*4);
    float* AH      = (float*)alloc((size_t)NV*DH*4);
    float* outvar  = (float*)alloc((size_t)NV*DO*4);
    float* holo    = (float*)alloc((size_t)NV*DO*4);
    int*   RnG     = (int*)  alloc(NB*MAXR*4);
    float* RwG     = (float*)alloc(NB*MAXR*4);
    int*   nRG     = (int*)  alloc(NB*4);
    float* dz2G    = (float*)alloc((size_t)NB*MAXR*DO*4);

    k_setup  <<<G_, 1024, 0, stream>>>(conArr, csr_off, csr_e, csr_v, dinv, nodeval, breakix);
    k_spmmX  <<<NN/4, 256, 0, stream>>>(vf, cf, dinv, conArr, csr_off, csr_v, AX);
    k_gemm1  <<<NN/32, 256, 0, stream>>>(AX, W1, b1, nodeval, S1);
    k_spmmH  <<<NV/2, 256, 0, stream>>>(S1, dinv, conArr, AH);
    k_gemm2ln<<<NV/32, 256, 0, stream>>>(AH, W2, b2, nodeval, gamma, beta, outvar, holo, out);
    k_corr_a <<<NB, 256, 0, stream>>>(breakix, dinv, conArr, csr_off, csr_v,
                                      S1, W1, W2, RnG, RwG, nRG, dz2G);
    k_corr_b <<<G_, 1024, 0, stream>>>(RnG, RwG, nRG, dz2G, breakix, dinv, conArr,
                                       csr_off, csr_v, outvar, holo, gamma, beta, out);
}

// Round 5
// 155.040 us; speedup vs baseline: 1.7661x; 1.7661x over previous
//
#include <hip/hip_runtime.h>
#include <hip/hip_bf16.h>

#define G_      4
#define NVP     3000
#define NCP     1000
#define DEG     8
#define NV      (G_*NVP)      // 12000
#define NC      (G_*NCP)      // 4000
#define NN      (NV+NC)       // 16000
#define NE      (NV*DEG)      // 96000
#define EPG     (NVP*DEG)     // 24000 edges per graph
#define DF      64
#define DH      128
#define DO      64
#define KB      8
#define NB      (G_*KB)       // 32 break nodes
#define MAXR    96
#define MAXJ    640

// ---------------- setup ----------------

// per-graph LDS histogram (no global zero pass needed)
__global__ __launch_bounds__(1024) void k_countG(const int* __restrict__ conArr,
                                                 int* __restrict__ condeg) {
    __shared__ int cnt[NCP];
    int g = blockIdx.x, tid = threadIdx.x;
    if (tid < NCP) cnt[tid] = 0;
    __syncthreads();
    int ebase = g * EPG;
    for (int e = tid; e < EPG; e += 1024)
        atomicAdd(&cnt[conArr[ebase + e] - g*NCP], 1);
    __syncthreads();
    if (tid < NCP) condeg[g*NCP + tid] = cnt[tid];
}

// single block: exclusive scan over all NC + dinvC + constraint nodeval
__global__ __launch_bounds__(1024) void k_scanA(const int* __restrict__ condeg,
    int* __restrict__ csr_off, int* __restrict__ csr_cur,
    float* __restrict__ dinvC, float* __restrict__ nodeval) {
    __shared__ int wsum[16];
    int tid = threadIdx.x, lane = tid & 63, w = tid >> 6;
    int c0 = tid*4;
    int v[4];
    #pragma unroll
    for (int q = 0; q < 4; ++q) v[q] = (c0+q < NC) ? condeg[c0+q] : 0;
    int s = v[0]+v[1]+v[2]+v[3];
    int x = s;
    for (int o = 1; o < 64; o <<= 1) { int y = __shfl_up(x, o); if (lane >= o) x += y; }
    if (lane == 63) wsum[w] = x;
    __syncthreads();
    if (tid == 0) { int run = 0; for (int t = 0; t < 16; ++t) { int z = wsum[t]; wsum[t] = run; run += z; } }
    __syncthreads();
    int run = x - s + wsum[w];
    const float dv3 = 1.0f/3.0f;
    #pragma unroll
    for (int q = 0; q < 4; ++q) {
        int c = c0 + q;
        if (c < NC) {
            csr_off[c] = run; csr_cur[c] = run;
            float dc = 1.0f / sqrtf((float)(v[q] + 1));
            dinvC[c] = dc;
            nodeval[NV + c] = (float)v[q] * (dc * dv3) + dc*dc;
            run += v[q];
        }
    }
    if (tid == 0) csr_off[NC] = NE;
}

// scatter var ids into CSR rows (order nondeterministic; only ulp-level effects)
__global__ __launch_bounds__(1024) void k_fill(const int* __restrict__ conArr,
                                               int* __restrict__ csr_cur,
                                               int* __restrict__ csr_v) {
    int e = blockIdx.x*1024 + threadIdx.x;
    if (e < NE) { int p = atomicAdd(&csr_cur[conArr[e]], 1); csr_v[p] = e >> 3; }
}

__global__ void k_nodevalV(const int* __restrict__ conArr, const float* __restrict__ dinvC,
                           float* __restrict__ nodeval) {
    int v = blockIdx.x*256 + threadIdx.x;
    if (v >= NV) return;
    const float dv3 = 1.0f/3.0f;
    float s = 0.f;
    int e0 = v*DEG;
    #pragma unroll
    for (int k = 0; k < DEG; ++k) s += dv3 * dinvC[conArr[e0+k]];
    nodeval[v] = s + dv3*dv3;
}

// per-graph top-8, LDS-resident, tie -> lower local position (matches lax.top_k)
__global__ __launch_bounds__(1024) void k_topk(const float* __restrict__ nodeval,
                                               int* __restrict__ breakix) {
    __shared__ float nvl[NVP + NCP];
    __shared__ float mv[16]; __shared__ int mp[16];
    int g = blockIdx.x, tid = threadIdx.x, lane = tid & 63, w = tid >> 6;
    for (int p = tid; p < NVP; p += 1024) nvl[p] = nodeval[g*NVP + p];
    for (int p = tid; p < NCP; p += 1024) nvl[NVP + p] = nodeval[NV + g*NCP + p];
    __syncthreads();
    for (int it = 0; it < KB; ++it) {
        float bv = -1e30f; int bp = 1 << 30;
        for (int p = tid; p < NVP+NCP; p += 1024) {
            float vv = nvl[p];
            if (vv > bv || (vv == bv && p < bp)) { bv = vv; bp = p; }
        }
        for (int o = 32; o > 0; o >>= 1) {
            float ov = __shfl_xor(bv, o); int op = __shfl_xor(bp, o);
            if (ov > bv || (ov == bv && op < bp)) { bv = ov; bp = op; }
        }
        if (lane == 0) { mv[w] = bv; mp[w] = bp; }
        __syncthreads();
        if (tid == 0) {
            float fv = mv[0]; int fp = mp[0];
            for (int t = 1; t < 16; ++t)
                if (mv[t] > fv || (mv[t] == fv && mp[t] < fp)) { fv = mv[t]; fp = mp[t]; }
            nvl[fp] = -1e30f;
            breakix[g*KB + it] = (fp < NVP) ? (g*NVP + fp) : (NV + g*NCP + (fp - NVP));
        }
        __syncthreads();
    }
}

// ---------------- forward ----------------

// AX = A_hat @ X  (N x 64), one row per wave
__global__ void k_spmmX(const float* __restrict__ vf, const float* __restrict__ cf,
                        const float* __restrict__ dinvC, const int* __restrict__ conArr,
                        const int* __restrict__ csr_off, const int* __restrict__ csr_v,
                        float* __restrict__ AX)
{
    int i = blockIdx.x*4 + (threadIdx.x >> 6);
    int lane = threadIdx.x & 63;
    const float dv3 = 1.0f/3.0f;
    float acc, di;
    if (i < NV) {
        di = dv3;
        acc = dv3 * vf[(size_t)i*DF + lane];
        int e0 = i*DEG;
        #pragma unroll
        for (int k = 0; k < DEG; ++k) {
            int c = conArr[e0+k];
            acc += dinvC[c] * cf[(size_t)c*DF + lane];
        }
    } else {
        int c = i - NV;
        di = dinvC[c];
        acc = di * cf[(size_t)c*DF + lane];
        int p0 = csr_off[c], p1 = csr_off[c+1];
        for (int p = p0; p < p1; ++p)
            acc += dv3 * vf[(size_t)csr_v[p]*DF + lane];
    }
    AX[(size_t)i*DF + lane] = di * acc;
}

// S1 = AX @ W1 + nodeval (x) b1    (NN x 128)
__global__ __launch_bounds__(256) void k_gemm1(const float* __restrict__ AX, const float* __restrict__ W1,
                        const float* __restrict__ b1, const float* __restrict__ nodeval,
                        float* __restrict__ S1)
{
    __shared__ float W1T[128*68];   // [c][k], padded
    __shared__ float AXs[32*68];
    int tid = threadIdx.x;
    for (int t = tid; t < 64*128; t += 256) {
        int k = t >> 7, c = t & 127;
        W1T[c*68 + k] = W1[t];
    }
    int r0 = blockIdx.x * 32;
    for (int t = tid; t < 32*16; t += 256) {
        int row = t >> 4, q = t & 15;
        *(float4*)&AXs[row*68 + q*4] = *(const float4*)&AX[(size_t)(r0+row)*DF + q*4];
    }
    __syncthreads();
    int tc = tid & 15, tr = tid >> 4;
    float acc[2][8];
    #pragma unroll
    for (int r = 0; r < 2; ++r)
        #pragma unroll
        for (int j = 0; j < 8; ++j) acc[r][j] = 0.f;
    #pragma unroll
    for (int k0 = 0; k0 < 64; k0 += 4) {
        float4 a0 = *(const float4*)&AXs[(tr*2+0)*68 + k0];
        float4 a1 = *(const float4*)&AXs[(tr*2+1)*68 + k0];
        #pragma unroll
        for (int j = 0; j < 8; ++j) {
            float4 wv = *(const float4*)&W1T[(tc + 16*j)*68 + k0];
            acc[0][j] += a0.x*wv.x + a0.y*wv.y + a0.z*wv.z + a0.w*wv.w;
            acc[1][j] += a1.x*wv.x + a1.y*wv.y + a1.z*wv.z + a1.w*wv.w;
        }
    }
    #pragma unroll
    for (int r = 0; r < 2; ++r) {
        int row = r0 + tr*2 + r;
        float nv_ = nodeval[row];
        #pragma unroll
        for (int j = 0; j < 8; ++j) {
            int col = tc + 16*j;
            S1[(size_t)row*DH + col] = acc[r][j] + nv_*b1[col];
        }
    }
}

// AH = A_hat @ relu(S1) at variable rows only (NV x 128)
__global__ void k_spmmH(const float* __restrict__ S1, const float* __restrict__ dinvC,
                        const int* __restrict__ conArr, float* __restrict__ AH)
{
    int v = blockIdx.x*2 + (threadIdx.x >> 7);
    int ch = threadIdx.x & 127;
    const float dv3 = 1.0f/3.0f;
    float acc = dv3 * fmaxf(S1[(size_t)v*DH + ch], 0.f);
    int e0 = v*DEG;
    #pragma unroll
    for (int k = 0; k < DEG; ++k) {
        int c = conArr[e0+k];
        acc += dinvC[c] * fmaxf(S1[(size_t)(NV + c)*DH + ch], 0.f);
    }
    AH[(size_t)v*DH + ch] = dv3 * acc;
}

// out rows: AH @ W2 + nodeval (x) b2, fused LayerNorm; writes outvar, holo, d_out
__global__ __launch_bounds__(256) void k_gemm2ln(const float* __restrict__ AH, const float* __restrict__ W2,
      const float* __restrict__ b2, const float* __restrict__ nodeval,
      const float* __restrict__ gamma, const float* __restrict__ beta,
      float* __restrict__ outvar, float* __restrict__ holo, float* __restrict__ out)
{
    __shared__ float W2T[64*132];   // [c][k], padded
    __shared__ float AHs[32*132];
    __shared__ float s2[32*68];
    int tid = threadIdx.x;
    for (int t = tid; t < 128*64; t += 256) {
        int k = t >> 6, c = t & 63;
        W2T[c*132 + k] = W2[t];
    }
    int r0 = blockIdx.x * 32;
    for (int t = tid; t < 32*32; t += 256) {
        int row = t >> 5, q = t & 31;
        *(float4*)&AHs[row*132 + q*4] = *(const float4*)&AH[(size_t)(r0+row)*DH + q*4];
    }
    __syncthreads();
    int tc = tid & 15, tr = tid >> 4;
    float acc[2][4];
    #pragma unroll
    for (int r = 0; r < 2; ++r)
        #pragma unroll
        for (int j = 0; j < 4; ++j) acc[r][j] = 0.f;
    #pragma unroll
    for (int k0 = 0; k0 < 128; k0 += 4) {
        float4 a0 = *(const float4*)&AHs[(tr*2+0)*132 + k0];
        float4 a1 = *(const float4*)&AHs[(tr*2+1)*132 + k0];
        #pragma unroll
        for (int j = 0; j < 4; ++j) {
            float4 wv = *(const float4*)&W2T[(tc + 16*j)*132 + k0];
            acc[0][j] += a0.x*wv.x + a0.y*wv.y + a0.z*wv.z + a0.w*wv.w;
            acc[1][j] += a1.x*wv.x + a1.y*wv.y + a1.z*wv.z + a1.w*wv.w;
        }
    }
    #pragma unroll
    for (int r = 0; r < 2; ++r) {
        int row = tr*2 + r;
        float nv_ = nodeval[r0 + row];
        #pragma unroll
        for (int j = 0; j < 4; ++j) {
            int col = tc + 16*j;
            s2[row*68 + col] = acc[r][j] + nv_*b2[col];
        }
    }
    __syncthreads();
    int lane = tid & 63, w = tid >> 6;
    float gm = gamma[lane], bt = beta[lane];
    for (int rr = 0; rr < 8; ++rr) {
        int row = w*8 + rr;
        int v = r0 + row;
        float xv = s2[row*68 + lane];
        float s = xv;
        for (int o = 32; o > 0; o >>= 1) s += __shfl_xor(s, o);
        float mu = s * (1.f/64.f);
        float d = xv - mu;
        float vs = d*d;
        for (int o = 32; o > 0; o >>= 1) vs += __shfl_xor(vs, o);
        float rstd = 1.0f / sqrtf(vs*(1.f/64.f) + 1e-5f);
        float h = d*rstd*gm + bt;
        outvar[(size_t)v*DO + lane] = xv;
        holo  [(size_t)v*DO + lane] = h;
        out   [(size_t)v*DO + lane] = h;
    }
}

// ---------------- corrections ----------------

// build R-list (value-sorted, multiplicity-weighted -> deterministic for any fill order)
// and dz2[r] = (relu(S1[r]+A[r,i]*w1last) - relu(S1[r])) @ W2
__global__ __launch_bounds__(256) void k_corr_a(const int* __restrict__ breakidx,
    const float* __restrict__ dinvC, const int* __restrict__ conArr,
    const int* __restrict__ csr_off, const int* __restrict__ csr_v,
    const float* __restrict__ S1, const float* __restrict__ W1, const float* __restrict__ W2,
    int* __restrict__ RnG, float* __restrict__ RwG, int* __restrict__ nRG, float* __restrict__ dz2G)
{
    __shared__ float W2s[128*64];
    __shared__ int Rn[MAXR];
    __shared__ float Rw[MAXR];
    __shared__ float dh[4][128];
    __shared__ int nR_s;
    int b = blockIdx.x, tid = threadIdx.x, lane = tid & 63;
    int i = breakidx[b];
    const float dv3 = 1.0f/3.0f;
    for (int t = tid; t < 128*64; t += 256) W2s[t] = W2[t];
    if (tid < 64) {
        if (i >= NV) {
            int c = i - NV;
            float di = dinvC[c];
            int p0 = csr_off[c], len = csr_off[c+1] - p0;
            if (len <= 64) {
                int v = (lane < len) ? csr_v[p0 + lane] : 0x7fffffff;
                int firstLane = 64, mult = 0;
                for (int m = 0; m < 64; ++m) {
                    int vm = __shfl(v, m);
                    if (vm == v) { mult++; if (m < firstLane) firstLane = m; }
                }
                bool head = (lane < len) && (firstLane == lane);
                unsigned long long hmask = __ballot(head);
                int hrk = 0;
                for (int m = 0; m < 64; ++m) {
                    if (!((hmask >> m) & 1)) continue;   // hmask uniform -> uniform branch
                    int vm = __shfl(v, m);
                    if (vm < v) hrk++;
                }
                if (head) { Rn[hrk] = v; Rw[hrk] = (float)mult * (dv3 * di); }
                int nH = __popcll(hmask);
                if (lane == 0) { Rn[nH] = i; Rw[nH] = di*di; nR_s = nH + 1; }
            } else if (lane == 0) {
                // defensive serial path (len>64: P~1e-11)
                int n = 0;
                for (int p = p0; p < p0 + len; ++p) {
                    int v = csr_v[p]; int f = -1;
                    for (int q = 0; q < n; ++q) if (Rn[q] == v) { f = q; break; }
                    if (f >= 0) Rw[f] += dv3 * di;
                    else if (n < MAXR-1) { Rn[n] = v; Rw[n] = dv3 * di; ++n; }
                }
                Rn[n] = i; Rw[n] = di*di; nR_s = n + 1;
            }
        } else if (lane == 0) {
            // variable break node (defensive; analytically never top-k)
            float di = dv3;
            int cn[DEG];
            for (int k = 0; k < DEG; ++k) cn[k] = NV + conArr[i*DEG + k];
            for (int a = 1; a < DEG; ++a) { int key = cn[a]; int bb = a-1;
                while (bb >= 0 && cn[bb] > key) { cn[bb+1] = cn[bb]; --bb; } cn[bb+1] = key; }
            int n = 0, k = 0;
            while (k < DEG) { int u = cn[k]; int m = 1; ++k;
                while (k < DEG && cn[k] == u) { ++m; ++k; }
                Rn[n] = u; Rw[n] = (float)m * dinvC[u - NV] * di; ++n; }
            Rn[n] = i; Rw[n] = di*di; nR_s = n + 1;
        }
    }
    __syncthreads();
    int nR = nR_s;
    for (int t = tid; t < nR; t += 256) { RnG[b*MAXR + t] = Rn[t]; RwG[b*MAXR + t] = Rw[t]; }
    if (tid == 0) nRG[b] = nR;
    for (int r0 = 0; r0 < nR; r0 += 4) {
        __syncthreads();
        for (int t = tid; t < 512; t += 256) {
            int ty = t >> 7, k = t & 127;
            int r = r0 + ty;
            if (r < nR) {
                float s1 = S1[(size_t)Rn[r]*DH + k];
                float a = s1 + Rw[r] * W1[64*128 + k];
                dh[ty][k] = fmaxf(a, 0.f) - fmaxf(s1, 0.f);
            }
        }
        __syncthreads();
        int ty2 = tid >> 6, c2 = tid & 63;
        int r2 = r0 + ty2;
        if (r2 < nR) {
            float acc = 0.f;
            #pragma unroll
            for (int kk = 0; kk < 128; ++kk) acc += dh[ty2][kk] * W2s[kk*64 + c2];
            dz2G[((size_t)b*MAXR + r2)*DO + c2] = acc;
        }
    }
}

// per graph serial over its 8 breaks: out[j] += 0.125*(LN(out+delta)-holo[j])
__global__ void k_corr_b(const int* __restrict__ RnG, const float* __restrict__ RwG,
                         const int* __restrict__ nRG, const float* __restrict__ dz2G,
                         const int* __restrict__ breakidx, const float* __restrict__ dinvC,
                         const int* __restrict__ conArr, const int* __restrict__ csr_off,
                         const int* __restrict__ csr_v,
                         const float* __restrict__ outvar, const float* __restrict__ holo,
                         const float* __restrict__ gamma, const float* __restrict__ beta,
                         float* __restrict__ out) {
    int g = blockIdx.x;
    int lane = threadIdx.x & 63, wv = threadIdx.x >> 6; // 16 waves
    const float dv3 = 1.0f/3.0f;
    __shared__ int Jn[MAXJ];
    __shared__ int nJ_s;
    for (int bi = 0; bi < KB; ++bi) {
        int b = g*KB + bi;
        int i = breakidx[b];
        int nR = nRG[b];
        if (i >= NV) {
            int nJ = nR - 1;
            const float* dzi = &dz2G[((size_t)b*MAXR + (nR-1))*DO];
            for (int j0 = wv; j0 < nJ; j0 += 16) {
                int j = RnG[b*MAXR + j0];
                float aji = RwG[b*MAXR + j0];
                float x = outvar[(size_t)j*DO + lane]
                        + aji * dzi[lane]
                        + dv3*dv3 * dz2G[((size_t)b*MAXR + j0)*DO + lane];
                float s = x; for (int o = 32; o > 0; o >>= 1) s += __shfl_xor(s, o);
                float mu = s * (1.f/64.f);
                float d = x - mu;
                float vs = d*d; for (int o = 32; o > 0; o >>= 1) vs += __shfl_xor(vs, o);
                float rstd = 1.0f / sqrtf(vs*(1.f/64.f) + 1e-5f);
                float hn = d*rstd*gamma[lane] + beta[lane];
                out[(size_t)j*DO + lane] += 0.125f * (hn - holo[(size_t)j*DO + lane]);
            }
        } else {
            if (threadIdx.x == 0) {
                int n = 0; Jn[n++] = i;
                for (int r = 0; r < nR-1; ++r) {
                    int c = RnG[b*MAXR + r] - NV;
                    for (int p = csr_off[c]; p < csr_off[c+1]; ++p) {
                        int u = csr_v[p];
                        bool found = false;
                        for (int q = 0; q < n; ++q) if (Jn[q] == u) { found = true; break; }
                        if (!found && n < MAXJ) Jn[n++] = u;
                    }
                }
                nJ_s = n;
            }
            __syncthreads();
            int nJ = nJ_s;
            for (int j0 = wv; j0 < nJ; j0 += 16) {
                int j = Jn[j0];
                float x = outvar[(size_t)j*DO + lane];
                for (int k = 0; k < DEG; ++k) {
                    int cn = NV + conArr[j*DEG + k];
                    for (int r = 0; r < nR-1; ++r)
                        if (RnG[b*MAXR + r] == cn) {
                            x += dv3 * dinvC[cn - NV] * dz2G[((size_t)b*MAXR + r)*DO + lane];
                            break;
                        }
                }
                if (j == i) x += dv3*dv3 * dz2G[((size_t)b*MAXR + nR-1)*DO + lane];
                float s = x; for (int o = 32; o > 0; o >>= 1) s += __shfl_xor(s, o);
                float mu = s * (1.f/64.f);
                float d = x - mu;
                float vs = d*d; for (int o = 32; o > 0; o >>= 1) vs += __shfl_xor(vs, o);
                float rstd = 1.0f / sqrtf(vs*(1.f/64.f) + 1e-5f);
                float hn = d*rstd*gamma[lane] + beta[lane];
                out[(size_t)j*DO + lane] += 0.125f * (hn - holo[(size_t)j*DO + lane]);
            }
        }
        __syncthreads();
    }
}

// ---------------- launch ----------------

extern "C" void kernel_launch(void* const* d_in, const int* in_sizes, int n_in,
                              void* d_out, int out_size, void* d_ws, size_t ws_size,
                              hipStream_t stream) {
    const float* vf    = (const float*)d_in[0];
    const float* cf    = (const float*)d_in[1];
    const float* W1    = (const float*)d_in[2];
    const float* b1    = (const float*)d_in[3];
    const float* W2    = (const float*)d_in[4];
    const float* b2    = (const float*)d_in[5];
    const float* gamma = (const float*)d_in[6];
    const float* beta  = (const float*)d_in[7];
    const int*   ei    = (const int*)d_in[8];   // [0..NE) = con, [NE..2NE) = var
    const int*   conArr = ei;
    float* out = (float*)d_out;

    char* ws = (char*)d_ws;
    size_t off = 0;
    auto alloc = [&](size_t bytes) { char* p = ws + off; off = (off + bytes + 255) & ~(size_t)255; return p; };
    float* dinvC   = (float*)alloc(NC*4);
    int*   condeg  = (int*)  alloc(NC*4);
    int*   csr_off = (int*)  alloc((NC+1)*4);
    int*   csr_cur = (int*)  alloc(NC*4);
    int*   csr_v   = (int*)  alloc(NE*4);
    float* nodeval = (float*)alloc(NN*4);
    int*   breakix = (int*)  alloc(NB*4);
    float* AX      = (float*)alloc((size_t)NN*DF*4);
    float* S1      = (float*)alloc((size_t)NN*DH*4);
    float* AH      = (float*)alloc((size_t)NV*DH*4);
    float* outvar  = (float*)alloc((size_t)NV*DO*4);
    float* holo    = (float*)alloc((size_t)NV*DO*4);
    int*   RnG     = (int*)  alloc(NB*MAXR*4);
    float* RwG     = (float*)alloc(NB*MAXR*4);
    int*   nRG     = (int*)  alloc(NB*4);
    float* dz2G    = (float*)alloc((size_t)NB*MAXR*DO*4);

    k_countG  <<<G_, 1024, 0, stream>>>(conArr, condeg);
    k_scanA   <<<1, 1024, 0, stream>>>(condeg, csr_off, csr_cur, dinvC, nodeval);
    k_fill    <<<(NE+1023)/1024, 1024, 0, stream>>>(conArr, csr_cur, csr_v);
    k_nodevalV<<<(NV+255)/256, 256, 0, stream>>>(conArr, dinvC, nodeval);
    k_topk    <<<G_, 1024, 0, stream>>>(nodeval, breakix);

    k_spmmX   <<<NN/4, 256, 0, stream>>>(vf, cf, dinvC, conArr, csr_off, csr_v, AX);
    k_gemm1   <<<NN/32, 256, 0, stream>>>(AX, W1, b1, nodeval, S1);
    k_spmmH   <<<NV/2, 256, 0, stream>>>(S1, dinvC, conArr, AH);
    k_gemm2ln <<<NV/32, 256, 0, stream>>>(AH, W2, b2, nodeval, gamma, beta, outvar, holo, out);

    k_corr_a  <<<NB, 256, 0, stream>>>(breakix, dinvC, conArr, csr_off, csr_v,
                                       S1, W1, W2, RnG, RwG, nRG, dz2G);
    k_corr_b  <<<G_, 1024, 0, stream>>>(RnG, RwG, nRG, dz2G, breakix, dinvC, conArr,
                                        csr_off, csr_v, outvar, holo, gamma, beta, out);
}